// Round 15
// baseline (66.566 us; speedup 1.0000x reference)
//
#include <hip/hip_runtime.h>

static constexpr int HD   = 128;   // head dim
static constexpr int HH   = 64;    // height
static constexpr int WW   = 64;    // width
static constexpr int ROWS = 2;     // tile rows per block
static constexpr int BLK  = 512;   // 4 threads per pixel (d-quarters)
static constexpr int HALO = ROWS + 2;     // 4 halo rows
static constexpr int DC   = 16;    // d-planes per chunk
static constexpr int NCH  = HD / DC;      // 8 K-chunks (then 8 V-chunks)
static constexpr int NT   = 16;    // 16 segments total: K0..K7, V0..V7
static constexpr int LSTR = 16;    // dense stride + XOR quad swizzle (R8-proven)
static constexpr float SCALE = 0.08838834764831845f;  // 128^-0.5

#define MEMFENCE asm volatile("" ::: "memory")

// R8 structure (42.9us: fp32, swizzled LSTR=16 dbuf, 4 blocks/CU, 9x b128
// reads, paired sector writeout) + a REAL 2-deep staging pipeline:
//  - raw s_barrier + lgkmcnt(0) instead of __syncthreads: __syncthreads drains
//    vmcnt(0), killing any cross-barrier prefetch. Raw barrier keeps loads
//    in flight; ds-write visibility only needs lgkmcnt(0).
//  - chunk t+2 loads issue at segment t into NAMED reg sets sA/sB (manual
//    2x unroll, static indexing per rule #20), consumed by ds_write at end of
//    segment t+1 (~2 compute phases ~500cy > L2/L3 latency).
//  - memory-clobber fences pin load issue order (loads are memory ops and
//    cannot cross, unlike R7's sinkable bare loads).
__global__ __launch_bounds__(BLK, 4) void natten3_kernel(
    const float* __restrict__ Q, const float* __restrict__ K,
    const float* __restrict__ V, float* __restrict__ O)
{
  __shared__ float buf[2][HALO * WW * LSTR];   // 2 x 16 KB

  const int tid = threadIdx.x;
  const int qf  = tid & 3;               // d-quarter
  const int px  = tid >> 2;              // 0..127 pixel in tile
  const int w   = px & 63;
  const int pr  = px >> 6;               // tile row 0/1

  // XCD-chunked swizzle: 1024 blocks, 128 consecutive tiles per XCD
  const int bid = blockIdx.x;
  const int swz = (bid & 7) * 128 + (bid >> 3);
  const int b   = swz >> 5;              // image
  const int h0  = (swz & 31) * ROWS;     // tile top row
  const int hh  = h0 + pr;

  const int plane = HH * WW;             // 4096
  const size_t img = (size_t)HD * plane;
  const float* Qb = Q + (size_t)b * img;
  const float* Kb = K + (size_t)b * img;
  const float* Vb = V + (size_t)b * img;
  const int qoff = hh * WW + w;
  const int dq   = 4 * qf;

  // staging map: 1024 float4-groups = 4 halo rows x 64 w x 4 pgroups, 2/thread
  int sg_g[2], sg_l[2];
  #pragma unroll
  for (int it = 0; it < 2; ++it) {
    const int idx  = it * BLK + tid;     // 0..1023
    const int ws   = idx & 63;
    const int rest = idx >> 6;           // 0..15
    const int is   = rest >> 2;          // halo row 0..3
    const int gs   = rest & 3;           // plane group 0..3
    const int grow = min(max(h0 - 1 + is, 0), HH - 1);
    sg_g[it] = gs * 4 * plane + grow * WW + ws;
    sg_l[it] = (is * WW + ws) * LSTR + 4 * (gs ^ ((ws >> 2) & 3));
  }

  // neighbor LDS offsets (my quarter, swizzled)
  int lofs[9];
  #pragma unroll
  for (int dh = 0; dh < 3; ++dh)
    #pragma unroll
    for (int dw = 0; dw < 3; ++dw) {
      const int cc = min(max(w + dw - 1, 0), WW - 1);
      lofs[dh * 3 + dw] = ((pr + dh) * WW + cc) * LSTR + 4 * (qf ^ ((cc >> 2) & 3));
    }

  // chunk t: 0..7 = K chunk t, 8..15 = V chunk t-8
  auto LOADS = [&](float* s, int t) {
    const float* cb = (t < NCH ? Kb : Vb) + (t & 7) * DC * plane;
    #pragma unroll
    for (int it = 0; it < 2; ++it)
      #pragma unroll
      for (int p = 0; p < 4; ++p)
        s[it * 4 + p] = cb[sg_g[it] + p * plane];
  };
  auto LOADQ = [&](float* qq, int c) {
    #pragma unroll
    for (int p = 0; p < 4; ++p)
      qq[p] = Qb[(c * DC + dq + p) * plane + qoff];
  };
  auto WRITE = [&](int slot, const float* s) {
    *(float4*)&buf[slot][sg_l[0]] = make_float4(s[0], s[1], s[2], s[3]);
    *(float4*)&buf[slot][sg_l[1]] = make_float4(s[4], s[5], s[6], s[7]);
  };
  auto BAR = [&]() {
    asm volatile("s_waitcnt lgkmcnt(0)" ::: "memory");  // my ds_writes visible
    __builtin_amdgcn_s_barrier();                       // no vmcnt drain
    MEMFENCE;
  };

  float sA[8], sB[8], q[4], qn[4];
  float logit[9];
  #pragma unroll
  for (int j = 0; j < 9; ++j) logit[j] = 0.0f;

  auto COMPK = [&](int slot) {
    const float* __restrict__ bc = buf[slot];
    #pragma unroll
    for (int j = 0; j < 9; ++j) {
      const float4 k4 = *(const float4*)&bc[lofs[j]];
      float acc = logit[j];
      acc = fmaf(q[0], k4.x, acc); acc = fmaf(q[1], k4.y, acc);
      acc = fmaf(q[2], k4.z, acc); acc = fmaf(q[3], k4.w, acc);
      logit[j] = acc;
    }
  };

  // ---- prologue: S0, Q0, S1 in flight; write S0 -> slot0
  LOADS(sA, 0);
  LOADQ(q, 0);
  LOADS(sB, 1);
  MEMFENCE;
  WRITE(0, sA);
  BAR();

  // ================= K segments (pairs) =================
  #pragma unroll 1
  for (int c = 0; c < NCH; c += 2) {
    // segment t=c (slot 0)
    LOADS(sA, c + 2);                    // c+2 <= 8 -> prefetches V0 at c=6
    LOADQ(qn, c + 1);                    // c+1 <= 7 always
    MEMFENCE;
    COMPK(0);
    WRITE(1, sB);                        // chunk c+1 -> slot1
    #pragma unroll
    for (int p = 0; p < 4; ++p) q[p] = qn[p];
    BAR();
    // segment t=c+1 (slot 1)
    LOADS(sB, c + 3);                    // c+3 <= 9 -> prefetches V1 at c=6
    if (c + 2 < NCH) LOADQ(qn, c + 2);
    MEMFENCE;
    COMPK(1);
    WRITE(0, sA);                        // chunk c+2 -> slot0
    if (c + 2 < NCH) {
      #pragma unroll
      for (int p = 0; p < 4; ++p) q[p] = qn[p];
    }
    BAR();
  }

  // ---- softmax (pure register math; V0 staged, V1 loaded, V2 pending)
  #pragma unroll
  for (int j = 0; j < 9; ++j) {
    logit[j] += __shfl_xor(logit[j], 1);
    logit[j] += __shfl_xor(logit[j], 2);
  }
  float att[9];
  {
    float msk[9];
    #pragma unroll
    for (int dh = 0; dh < 3; ++dh)
      #pragma unroll
      for (int dw = 0; dw < 3; ++dw) {
        const int j = dh * 3 + dw;
        const int r = hh + dh - 1, c = w + dw - 1;
        msk[j] = (r >= 0 && r < HH && c >= 0 && c < WW) ? 1.0f : 0.0f;
      }
    #pragma unroll
    for (int j = 0; j < 9; ++j) logit[j] = msk[j] * logit[j] * SCALE;
    float m = logit[0];
    #pragma unroll
    for (int j = 1; j < 9; ++j) m = fmaxf(m, logit[j]);
    float Z = 0.0f;
    #pragma unroll
    for (int j = 0; j < 9; ++j) { att[j] = __expf(logit[j] - m); Z += att[j]; }
    const float rZ = 1.0f / Z;
    #pragma unroll
    for (int j = 0; j < 9; ++j) att[j] *= rZ * msk[j];
  }

  // ================= V segments (pairs) =================
  const size_t obase = ((size_t)b * plane + (size_t)h0 * WW) * HD;
  #pragma unroll 1
  for (int t = NCH; t < NT; t += 2) {
    float oA0 = 0.f, oA1 = 0.f, oA2 = 0.f, oA3 = 0.f;
    float oB0 = 0.f, oB1 = 0.f, oB2 = 0.f, oB3 = 0.f;
    // segment t (slot 0)
    if (t + 2 < NT) LOADS(sA, t + 2);
    MEMFENCE;
    {
      const float* __restrict__ bc = buf[0];
      #pragma unroll
      for (int j = 0; j < 9; ++j) {
        const float4 v4 = *(const float4*)&bc[lofs[j]];
        const float a = att[j];
        oA0 = fmaf(a, v4.x, oA0); oA1 = fmaf(a, v4.y, oA1);
        oA2 = fmaf(a, v4.z, oA2); oA3 = fmaf(a, v4.w, oA3);
      }
    }
    WRITE(1, sB);                        // chunk t+1 -> slot1
    BAR();
    // segment t+1 (slot 1)
    if (t + 3 < NT) LOADS(sB, t + 3);
    MEMFENCE;
    {
      const float* __restrict__ bc = buf[1];
      #pragma unroll
      for (int j = 0; j < 9; ++j) {
        const float4 v4 = *(const float4*)&bc[lofs[j]];
        const float a = att[j];
        oB0 = fmaf(a, v4.x, oB0); oB1 = fmaf(a, v4.y, oB1);
        oB2 = fmaf(a, v4.z, oB2); oB3 = fmaf(a, v4.w, oB3);
      }
    }
    // paired writeout: quad covers one full 128B sector of its pixel
    const size_t oa = obase + (size_t)px * HD + (size_t)(t - NCH) * DC + dq;
    *(float4*)&O[oa]      = make_float4(oA0, oA1, oA2, oA3);
    *(float4*)&O[oa + DC] = make_float4(oB0, oB1, oB2, oB3);
    if (t + 2 < NT) {
      WRITE(0, sA);                      // chunk t+2 -> slot0
      BAR();
    }
  }
}

extern "C" void kernel_launch(void* const* d_in, const int* in_sizes, int n_in,
                              void* d_out, int out_size, void* d_ws, size_t ws_size,
                              hipStream_t stream) {
  const float* q = (const float*)d_in[0];
  const float* k = (const float*)d_in[1];
  const float* v = (const float*)d_in[2];
  float* o = (float*)d_out;
  const int nblocks = 32 * (HH / ROWS);   // 1024
  natten3_kernel<<<dim3(nblocks), dim3(BLK), 0, stream>>>(q, k, v, o);
}